// Round 5
// baseline (113.679 us; speedup 1.0000x reference)
//
#include <hip/hip_runtime.h>

#define N_POINTS  131072
#define N_ANCHORS 2048
#define CHUNKS    32
#define M_PER     (N_ANCHORS / CHUNKS)   // 64 anchors per block
#define THREADS   256
#define PTS       4                      // points per thread
#define PT_STRIDE (N_POINTS / PTS)       // 32768
#define LOG2E     1.4426950408889634f

// Compact per-anchor folded constants (32 B, s_load_dwordx8 friendly).
//   arg(n,m) = q + r.x_n + sp*|x_n|^2 ;  K = exp2(arg) ; out += cf*K
struct __align__(32) Anchor {
    float r0, r1, r2, q, sp, cf, p0, p1;
};

__global__ void precompute_anchors(const float* __restrict__ aloc,
                                   const float* __restrict__ coeffs,
                                   const float* __restrict__ params,
                                   Anchor* __restrict__ A) {
    int m = blockIdx.x * blockDim.x + threadIdx.x;
    if (m >= N_ANCHORS) return;
    const float a0 = aloc[3 * m + 0];
    const float a1 = aloc[3 * m + 1];
    const float a2 = aloc[3 * m + 2];
    const float w  = params[m];
    const float sp = -(0.5f * LOG2E) / (w * w);
    Anchor out;
    out.r0 = -2.0f * sp * a0;
    out.r1 = -2.0f * sp * a1;
    out.r2 = -2.0f * sp * a2;
    out.q  = sp * (a0 * a0 + a1 * a1 + a2 * a2);
    out.sp = sp;
    out.cf = coeffs[m];
    out.p0 = 0.0f;
    out.p1 = 0.0f;
    A[m] = out;
}

// ---------------------------------------------------------------------------
// Grid (128, 32) x 256 = 4096 blocks (2x oversubscription of the 2048
// co-resident slots) so the CU scheduler always has runnable waves.
// Scalar f32 math: per point-anchor 4 fma + 1 exp2 + 1 acc-fma, constants
// in SGPRs (<=1 SGPR source per fma; q hoisted to VGPR once per anchor).
// ---------------------------------------------------------------------------
__global__ __launch_bounds__(256, 8) void linear_potential_main(
    const float* __restrict__ xloc,
    const Anchor* __restrict__ anchors,
    float* __restrict__ out)
{
    const int t   = threadIdx.x;
    const int tid = blockIdx.x * THREADS + t;     // [0, 32768)
    const int n0 = tid;
    const int n1 = tid + PT_STRIDE;
    const int n2 = tid + 2 * PT_STRIDE;
    const int n3 = tid + 3 * PT_STRIDE;

    const float x0 = xloc[3 * n0 + 0], y0 = xloc[3 * n0 + 1], z0 = xloc[3 * n0 + 2];
    const float x1 = xloc[3 * n1 + 0], y1 = xloc[3 * n1 + 1], z1 = xloc[3 * n1 + 2];
    const float x2 = xloc[3 * n2 + 0], y2 = xloc[3 * n2 + 1], z2 = xloc[3 * n2 + 2];
    const float x3 = xloc[3 * n3 + 0], y3 = xloc[3 * n3 + 1], z3 = xloc[3 * n3 + 2];

    const float ss0 = fmaf(x0, x0, fmaf(y0, y0, z0 * z0));
    const float ss1 = fmaf(x1, x1, fmaf(y1, y1, z1 * z1));
    const float ss2 = fmaf(x2, x2, fmaf(y2, y2, z2 * z2));
    const float ss3 = fmaf(x3, x3, fmaf(y3, y3, z3 * z3));

    float acc0 = 0.0f, acc1 = 0.0f, acc2 = 0.0f, acc3 = 0.0f;

    const Anchor* __restrict__ ach = anchors + blockIdx.y * M_PER;

    #pragma unroll 8
    for (int mm = 0; mm < M_PER; ++mm) {
        const float r0 = ach[mm].r0;
        const float r1 = ach[mm].r1;
        const float r2 = ach[mm].r2;
        const float q  = ach[mm].q;
        const float sp = ach[mm].sp;
        const float cf = ach[mm].cf;

        const float a0 = fmaf(r0, x0, fmaf(r1, y0, fmaf(r2, z0, fmaf(sp, ss0, q))));
        const float a1 = fmaf(r0, x1, fmaf(r1, y1, fmaf(r2, z1, fmaf(sp, ss1, q))));
        const float a2 = fmaf(r0, x2, fmaf(r1, y2, fmaf(r2, z2, fmaf(sp, ss2, q))));
        const float a3 = fmaf(r0, x3, fmaf(r1, y3, fmaf(r2, z3, fmaf(sp, ss3, q))));

        const float e0 = __builtin_amdgcn_exp2f(a0);
        const float e1 = __builtin_amdgcn_exp2f(a1);
        const float e2 = __builtin_amdgcn_exp2f(a2);
        const float e3 = __builtin_amdgcn_exp2f(a3);

        acc0 = fmaf(cf, e0, acc0);
        acc1 = fmaf(cf, e1, acc1);
        acc2 = fmaf(cf, e2, acc2);
        acc3 = fmaf(cf, e3, acc3);
    }

    atomicAdd(&out[n0], acc0);
    atomicAdd(&out[n1], acc1);
    atomicAdd(&out[n2], acc2);
    atomicAdd(&out[n3], acc3);
}

extern "C" void kernel_launch(void* const* d_in, const int* in_sizes, int n_in,
                              void* d_out, int out_size, void* d_ws, size_t ws_size,
                              hipStream_t stream) {
    const float* xloc   = (const float*)d_in[0];   // [131072,3]
    const float* aloc   = (const float*)d_in[1];   // [2048,3]
    const float* coeffs = (const float*)d_in[2];   // [2048]
    const float* params = (const float*)d_in[3];   // [2048]
    float* out = (float*)d_out;                    // [131072] f32

    Anchor* A = (Anchor*)d_ws;                     // 2048 * 32 B = 64 KiB

    // d_out is poisoned 0xAA before every timed call -> zero it (capturable).
    hipMemsetAsync(d_out, 0, N_POINTS * sizeof(float), stream);

    precompute_anchors<<<dim3(N_ANCHORS / 256), dim3(256), 0, stream>>>(
        aloc, coeffs, params, A);

    linear_potential_main<<<dim3(N_POINTS / (THREADS * PTS), CHUNKS),
                            dim3(THREADS), 0, stream>>>(
        xloc, A, out);
}

// Round 6
// 98.702 us; speedup vs baseline: 1.1517x; 1.1517x over previous
//
#include <hip/hip_runtime.h>

#define N_POINTS  131072
#define N_ANCHORS 2048
#define CHUNKS    32
#define M_PER     (N_ANCHORS / CHUNKS)   // 64 anchors per block
#define THREADS   256
#define PTS       4                      // points per thread
#define PT_STRIDE (N_POINTS / PTS)       // 32768
#define LOG2E     1.4426950408889634f

typedef float v2f __attribute__((ext_vector_type(2)));

// Anchor constants kept DUPLICATED ({v,v}) in LDS so a uniform-address
// ds_read_b64 delivers each one straight into an even-aligned VGPR pair:
// v_pk_fma_f32 then runs with all-VGPR sources -- zero v_mov broadcast
// overhead, zero SGPR-source restrictions. Uniform address = LDS broadcast,
// 0 bank conflicts (verified R2/R3).
struct __align__(16) AnchorLds {
    v2f r0, r1, r2, q, sp, cf;   // 48 B
    v2f pad0, pad1;              // pad to 64 B (clean ds offsets)
};

// ---------------------------------------------------------------------------
// Fused kernel. Grid (32, 32) x 256 = 1024... see launch: (N/(256*4), 32)
// = (128, 32) = 4096 blocks -> 2 rounds/CU for dispatch smoothing.
// Block: fold its 64-anchor chunk into LDS (threads 0..63), sync, then each
// thread evaluates 4 points (2 v2f pairs) x 64 anchors.
//   arg(n,m) = q + r.x_n + sp*|x_n|^2 ;  K = exp2(arg) ; out += cf*K
// Per-iter VALU: 10 v_pk_fma_f32 + 4 v_exp_f32. Everything else off-pipe.
// ---------------------------------------------------------------------------
__global__ __launch_bounds__(256, 8) void linear_potential_main(
    const float* __restrict__ xloc,
    const float* __restrict__ aloc,
    const float* __restrict__ coeffs,
    const float* __restrict__ params,
    float* __restrict__ out)
{
    __shared__ AnchorLds sA[M_PER];      // 4 KiB

    const int t = threadIdx.x;

    if (t < M_PER) {
        const int m  = blockIdx.y * M_PER + t;
        const float a0 = aloc[3 * m + 0];
        const float a1 = aloc[3 * m + 1];
        const float a2 = aloc[3 * m + 2];
        const float w  = params[m];
        const float sp = -(0.5f * LOG2E) / (w * w);
        const float r0 = -2.0f * sp * a0;
        const float r1 = -2.0f * sp * a1;
        const float r2 = -2.0f * sp * a2;
        const float q  = sp * (a0 * a0 + a1 * a1 + a2 * a2);
        const float cf = coeffs[m];
        sA[t].r0 = (v2f){r0, r0};
        sA[t].r1 = (v2f){r1, r1};
        sA[t].r2 = (v2f){r2, r2};
        sA[t].q  = (v2f){q,  q};
        sA[t].sp = (v2f){sp, sp};
        sA[t].cf = (v2f){cf, cf};
    }
    __syncthreads();

    const int tid = blockIdx.x * THREADS + t;     // [0, 32768)
    const int n0 = tid;
    const int n1 = tid + PT_STRIDE;
    const int n2 = tid + 2 * PT_STRIDE;
    const int n3 = tid + 3 * PT_STRIDE;

    const v2f xa = { xloc[3 * n0 + 0], xloc[3 * n1 + 0] };
    const v2f ya = { xloc[3 * n0 + 1], xloc[3 * n1 + 1] };
    const v2f za = { xloc[3 * n0 + 2], xloc[3 * n1 + 2] };
    const v2f xb = { xloc[3 * n2 + 0], xloc[3 * n3 + 0] };
    const v2f yb = { xloc[3 * n2 + 1], xloc[3 * n3 + 1] };
    const v2f zb = { xloc[3 * n2 + 2], xloc[3 * n3 + 2] };

    const v2f ssa = __builtin_elementwise_fma(xa, xa,
                    __builtin_elementwise_fma(ya, ya, za * za));
    const v2f ssb = __builtin_elementwise_fma(xb, xb,
                    __builtin_elementwise_fma(yb, yb, zb * zb));

    v2f acca = { 0.0f, 0.0f };
    v2f accb = { 0.0f, 0.0f };

    #pragma unroll 8
    for (int mm = 0; mm < M_PER; ++mm) {
        const v2f r0 = sA[mm].r0;
        const v2f r1 = sA[mm].r1;
        const v2f r2 = sA[mm].r2;
        const v2f q  = sA[mm].q;
        const v2f sp = sA[mm].sp;
        const v2f cf = sA[mm].cf;

        v2f arga = __builtin_elementwise_fma(sp, ssa, q);
        arga     = __builtin_elementwise_fma(r0, xa, arga);
        arga     = __builtin_elementwise_fma(r1, ya, arga);
        arga     = __builtin_elementwise_fma(r2, za, arga);

        v2f argb = __builtin_elementwise_fma(sp, ssb, q);
        argb     = __builtin_elementwise_fma(r0, xb, argb);
        argb     = __builtin_elementwise_fma(r1, yb, argb);
        argb     = __builtin_elementwise_fma(r2, zb, argb);

        v2f ea = { __builtin_amdgcn_exp2f(arga.x), __builtin_amdgcn_exp2f(arga.y) };
        v2f eb = { __builtin_amdgcn_exp2f(argb.x), __builtin_amdgcn_exp2f(argb.y) };

        acca = __builtin_elementwise_fma(cf, ea, acca);
        accb = __builtin_elementwise_fma(cf, eb, accb);
    }

    atomicAdd(&out[n0], acca.x);
    atomicAdd(&out[n1], acca.y);
    atomicAdd(&out[n2], accb.x);
    atomicAdd(&out[n3], accb.y);
}

extern "C" void kernel_launch(void* const* d_in, const int* in_sizes, int n_in,
                              void* d_out, int out_size, void* d_ws, size_t ws_size,
                              hipStream_t stream) {
    const float* xloc   = (const float*)d_in[0];   // [131072,3]
    const float* aloc   = (const float*)d_in[1];   // [2048,3]
    const float* coeffs = (const float*)d_in[2];   // [2048]
    const float* params = (const float*)d_in[3];   // [2048]
    float* out = (float*)d_out;                    // [131072] f32

    // d_out is poisoned 0xAA before every timed call -> zero it (capturable).
    hipMemsetAsync(d_out, 0, N_POINTS * sizeof(float), stream);

    linear_potential_main<<<dim3(N_POINTS / (THREADS * PTS), CHUNKS),
                            dim3(THREADS), 0, stream>>>(
        xloc, aloc, coeffs, params, out);
}